// Round 1
// baseline (13931.148 us; speedup 1.0000x reference)
//
#include <hip/hip_runtime.h>
#include <cstdint>
#include <cstddef>

#define S 4096
#define E 256
#define H 256
#define T 32
#define START_TAG 30
#define STOP_TAG 31
#define NEGV (-10000.0f)

typedef _Float16 half_t;
typedef _Float16 h2 __attribute__((ext_vector_type(2)));
typedef _Float16 f16x8 __attribute__((ext_vector_type(8)));
typedef float f32x4 __attribute__((ext_vector_type(4)));

__device__ __forceinline__ h2 f2h2(float a, float b) {
    h2 r; r[0] = (half_t)a; r[1] = (half_t)b; return r;
}
__device__ __forceinline__ unsigned short f2h16(float f) {
    half_t h = (half_t)f;
    unsigned short u; __builtin_memcpy(&u, &h, 2); return u;
}
__device__ __forceinline__ float h16tof(unsigned short u) {
    half_t h; __builtin_memcpy(&h, &u, 2); return (float)h;
}

__device__ __forceinline__ float sigmoidf_(float x) {
    return 1.0f / (1.0f + __expf(-x));
}
__device__ __forceinline__ float tanhf_(float x) {
    return 1.0f - 2.0f / (__expf(2.0f * x) + 1.0f);
}

__device__ __forceinline__ f16x8 cvt8(float4 a, float4 b) {
    f16x8 v;
    v[0] = (_Float16)a.x; v[1] = (_Float16)a.y; v[2] = (_Float16)a.z; v[3] = (_Float16)a.w;
    v[4] = (_Float16)b.x; v[5] = (_Float16)b.y; v[6] = (_Float16)b.z; v[7] = (_Float16)b.w;
    return v;
}

// ---------------------------------------------------------------------------
// Kernel 1: xg packed f16 per (dir, t, unit): u64 = {i, f, g, o} pre-activations
// ---------------------------------------------------------------------------
#define SBLK 16
__global__ __launch_bounds__(256) void xg_kernel(
    const int* __restrict__ sent, const float* __restrict__ emb,
    const float* __restrict__ w_ih_f, const float* __restrict__ b_f,
    const float* __restrict__ w_ih_b, const float* __restrict__ b_b,
    unsigned short* __restrict__ xg16s)   // [2][S][256][4] ushort
{
    const int dir = blockIdx.y;
    const int t0 = blockIdx.x * SBLK;
    const float* w_ih = dir ? w_ih_b : w_ih_f;
    const float* bias = dir ? b_b : b_f;

    __shared__ float embs[SBLK][E];   // 16 KB
    for (int p = threadIdx.x; p < SBLK * (E / 4); p += 256) {
        int r = p >> 6, kq = p & 63;
        int t = t0 + r;
        int tt = dir ? (S - 1 - t) : t;
        int tok = sent[tt];
        float4 v = *(const float4*)(emb + (size_t)tok * E + 4 * kq);
        *(float4*)&embs[r][4 * kq] = v;
    }
    __syncthreads();

    for (int jj = 0; jj < 4; ++jj) {           // jj = gate index G
        int j = jj * 256 + threadIdx.x;        // gate row
        const float* wrow = w_ih + (size_t)j * E;
        float bv = bias[j];
        float acc[SBLK];
        #pragma unroll
        for (int t = 0; t < SBLK; ++t) acc[t] = bv;

        for (int kc = 0; kc < E / 16; ++kc) {
            float w[16];
            float4 a0 = *(const float4*)(wrow + kc * 16);
            float4 a1 = *(const float4*)(wrow + kc * 16 + 4);
            float4 a2 = *(const float4*)(wrow + kc * 16 + 8);
            float4 a3 = *(const float4*)(wrow + kc * 16 + 12);
            w[0] = a0.x; w[1] = a0.y; w[2] = a0.z; w[3] = a0.w;
            w[4] = a1.x; w[5] = a1.y; w[6] = a1.z; w[7] = a1.w;
            w[8] = a2.x; w[9] = a2.y; w[10] = a2.z; w[11] = a2.w;
            w[12] = a3.x; w[13] = a3.y; w[14] = a3.z; w[15] = a3.w;
            #pragma unroll
            for (int t = 0; t < SBLK; ++t) {
                const float* er = &embs[t][kc * 16];
                float s = 0.f;
                #pragma unroll
                for (int q = 0; q < 16; ++q) s += w[q] * er[q];
                acc[t] += s;
            }
        }
        const int u = threadIdx.x;   // unit
        #pragma unroll
        for (int t = 0; t < SBLK; ++t) {
            size_t base = (((size_t)dir * S + (size_t)(t0 + t)) * 256 + u) * 4 + jj;
            xg16s[base] = f2h16(acc[t]);
        }
    }
}

// ---------------------------------------------------------------------------
// Kernel 2: persistent per-direction LSTM via MFMA. 2 blocks x 512 threads.
//
// Per wave w (8 waves): 32 units w*32..w*32+31. 8 MFMA chains; chain c
// computes gate (c&3) of unit w*32 + 2*(lane&15) + (c>>2).
//   A = h broadcast to all 16 rows  (lane provides h[kt*32 + (lane>>4)*8 + j])
//   B = w_hh rows (permuted)        (lane provides W[row(c,n)][kt*32+(lane>>4)*8+j])
//   D col n = lane&15 -> every lane holds gates of units 2n, 2n+1 (all regs equal).
// Weights fully register-resident (8 chains x 8 ktiles x f16x8 = 256 regs -> AGPRs).
// LDS traffic per wave per step: 8 broadcast ds_read_b128 + 1 ds_write_b16 pair.
// ---------------------------------------------------------------------------
__global__ __launch_bounds__(512) void lstm_kernel(
    const float* __restrict__ h0, const float* __restrict__ c0,
    const float* __restrict__ w_hh_f, const float* __restrict__ w_hh_b,
    const unsigned long long* __restrict__ xgq, float* __restrict__ hs)
{
    __shared__ __align__(16) _Float16 hbuf[2][256];   // 1 KB double-buffered h (f16)

    const int dir  = blockIdx.x;
    const int tid  = threadIdx.x;
    const int lane = tid & 63;
    const int w    = tid >> 6;          // wave 0..7
    const int n    = lane & 15;         // MFMA column
    const int kg   = lane >> 4;         // k-group 0..3
    const float* w_hh = dir ? w_hh_b : w_hh_f;

    // ---- load weight B-fragments into registers (one-time) ----
    f16x8 wB[8][8];
    #pragma unroll
    for (int c = 0; c < 8; ++c) {
        const int row = (c & 3) * 256 + w * 32 + 2 * n + (c >> 2);
        const float* pr = w_hh + (size_t)row * H + kg * 8;
        #pragma unroll
        for (int kt = 0; kt < 8; ++kt) {
            float4 a = *(const float4*)(pr + kt * 32);
            float4 b = *(const float4*)(pr + kt * 32 + 4);
            wB[c][kt] = cvt8(a, b);
        }
    }

    // this lane owns unit u_own (2x redundancy across lanes)
    const int  u_a    = w * 32 + 2 * n;
    const bool hiU    = (kg >= 2);
    const int  u_own  = u_a + (hiU ? 1 : 0);
    const bool writer = (kg == 0) || (kg == 2);
    float cst = c0[dir * H + u_own];

    if (tid < 256) hbuf[0][tid] = (_Float16)h0[dir * H + tid];

    const unsigned long long* xgl = xgq + (size_t)dir * S * 256 + u_a;
    uint4 xgw = *(const uint4*)xgl;     // units {u_a, u_a+1} x 4 gates, f16

    __syncthreads();

    for (int t = 0; t < S; ++t) {
        // A-fragments: broadcast reads of current h buffer
        const _Float16* hb = &hbuf[t & 1][0];
        f16x8 hA[8];
        #pragma unroll
        for (int kt = 0; kt < 8; ++kt)
            hA[kt] = *(const f16x8*)(hb + kt * 32 + kg * 8);

        // unpack xg pre-activations; chain c <-> half c of the 16 bytes
        float xf[8];
        xf[0] = h16tof((unsigned short)(xgw.x & 0xffffu));
        xf[1] = h16tof((unsigned short)(xgw.x >> 16));
        xf[2] = h16tof((unsigned short)(xgw.y & 0xffffu));
        xf[3] = h16tof((unsigned short)(xgw.y >> 16));
        xf[4] = h16tof((unsigned short)(xgw.z & 0xffffu));
        xf[5] = h16tof((unsigned short)(xgw.z >> 16));
        xf[6] = h16tof((unsigned short)(xgw.w & 0xffffu));
        xf[7] = h16tof((unsigned short)(xgw.w >> 16));

        f32x4 acc[8];
        #pragma unroll
        for (int c = 0; c < 8; ++c) {
            f32x4 z = { xf[c], xf[c], xf[c], xf[c] };
            acc[c] = z;
        }

        // prefetch next step's xg during compute
        const int tn = (t + 1 < S) ? (t + 1) : t;
        uint4 xgn = *(const uint4*)(xgl + (size_t)tn * 256);

        #pragma unroll
        for (int kt = 0; kt < 8; ++kt) {
            #pragma unroll
            for (int c = 0; c < 8; ++c)
                acc[c] = __builtin_amdgcn_mfma_f32_16x16x32_f16(hA[kt], wB[c][kt], acc[c], 0, 0, 0);
        }

        // gates for this lane's unit (static acc indices, uniform-per-lane select)
        float gi = hiU ? acc[4][0] : acc[0][0];
        float gf = hiU ? acc[5][0] : acc[1][0];
        float gg = hiU ? acc[6][0] : acc[2][0];
        float go = hiU ? acc[7][0] : acc[3][0];

        float iv = sigmoidf_(gi);
        float fv = sigmoidf_(gf);
        float gv = tanhf_(gg);
        float ov = sigmoidf_(go);
        cst = fv * cst + iv * gv;
        float hv = ov * tanhf_(cst);

        if (writer) {
            hbuf[(t + 1) & 1][u_own] = (_Float16)hv;
            int row = dir ? (S - 1 - t) : t;
            hs[(size_t)row * 512 + dir * 256 + u_own] = hv;
        }
        xgw = xgn;
        __syncthreads();
    }
}

// ---------------------------------------------------------------------------
// Kernel 3: feats[t][tag] = lin_b[tag] + sum_k hs[t][k] * lin_w[tag][k]
// ---------------------------------------------------------------------------
__global__ __launch_bounds__(256) void feats_kernel(
    const float* __restrict__ hs, const float* __restrict__ lin_w,
    const float* __restrict__ lin_b, float* __restrict__ feats)
{
    const int t0 = blockIdx.x * 8;
    __shared__ float rows[8][512];   // 16 KB
    for (int p = threadIdx.x; p < 8 * 128; p += 256) {
        int r = p >> 7, sg = p & 127;
        float4 v = *(const float4*)(hs + (size_t)(t0 + r) * 512 + sg * 4);
        *(float4*)&rows[r][sg * 4] = v;
    }
    __syncthreads();

    const int tl = threadIdx.x >> 5, tag = threadIdx.x & 31;
    const float* lw = lin_w + (size_t)tag * 512;
    float acc = lin_b[tag];
    for (int kc = 0; kc < 32; ++kc) {
        float4 a0 = *(const float4*)(lw + kc * 16);
        float4 a1 = *(const float4*)(lw + kc * 16 + 4);
        float4 a2 = *(const float4*)(lw + kc * 16 + 8);
        float4 a3 = *(const float4*)(lw + kc * 16 + 12);
        const float* er = &rows[tl][kc * 16];
        acc += a0.x * er[0] + a0.y * er[1] + a0.z * er[2] + a0.w * er[3];
        acc += a1.x * er[4] + a1.y * er[5] + a1.z * er[6] + a1.w * er[7];
        acc += a2.x * er[8] + a2.y * er[9] + a2.z * er[10] + a2.w * er[11];
        acc += a3.x * er[12] + a3.y * er[13] + a3.z * er[14] + a3.w * er[15];
    }
    feats[(size_t)(t0 + tl) * T + tag] = acc;
}

// ---------------------------------------------------------------------------
// Kernel 4a: per-chunk (max,+) transfer matrices. Block c folds steps
// c*64..c*64+63 into M_c[32][32]; A_t[n][p] = trans[n][p] + feats[t][n].
// ---------------------------------------------------------------------------
#define VCS 64
#define VNC (S / VCS)    // 64
__global__ __launch_bounds__(256) void vit_chunk_kernel(
    const float* __restrict__ feats, const float* __restrict__ trans,
    float* __restrict__ gM)
{
    const int c = blockIdx.x;
    const int tid = threadIdx.x;
    const int n = tid >> 3, p0 = (tid & 7) * 4;
    __shared__ float Mb[2][32][36];   // padded rows (144 B, 16-aligned)

    float tr[32];
    #pragma unroll
    for (int k = 0; k < 32; ++k) tr[k] = trans[n * 32 + k];

    float f0 = feats[(size_t)(c * VCS) * 32 + n];
    float4 cur = { tr[p0] + f0, tr[p0 + 1] + f0, tr[p0 + 2] + f0, tr[p0 + 3] + f0 };
    *(float4*)&Mb[0][n][p0] = cur;
    __syncthreads();

    int rb = 0;
    for (int s = 1; s < VCS; ++s) {
        float fn = feats[(size_t)(c * VCS + s) * 32 + n];
        float4 acc = { -3.0e38f, -3.0e38f, -3.0e38f, -3.0e38f };
        #pragma unroll 8
        for (int k = 0; k < 32; ++k) {
            float4 mo = *(const float4*)&Mb[rb][k][p0];
            float tk = tr[k];
            acc.x = fmaxf(acc.x, tk + mo.x);
            acc.y = fmaxf(acc.y, tk + mo.y);
            acc.z = fmaxf(acc.z, tk + mo.z);
            acc.w = fmaxf(acc.w, tk + mo.w);
        }
        acc.x += fn; acc.y += fn; acc.z += fn; acc.w += fn;
        cur = acc;
        *(float4*)&Mb[rb ^ 1][n][p0] = acc;
        rb ^= 1;
        __syncthreads();
    }
    *(float4*)(gM + (size_t)c * 1024 + n * 32 + p0) = cur;
}

// ---------------------------------------------------------------------------
// Kernel 4b: prefix-apply chunk matrices -> boundary fvs; chunk-parallel
// rescan for backpointers; 3-phase backtrack. OUTPUT FLOAT32.
// ---------------------------------------------------------------------------
__global__ __launch_bounds__(1024) void vit_combine_kernel(
    const float* __restrict__ feats, const float* __restrict__ trans,
    const float* __restrict__ gM, unsigned char* __restrict__ gbp,
    float* __restrict__ out)
{
    __shared__ float MS[1024];
    __shared__ __align__(16) float bfv[VNC + 1][32];
    __shared__ __align__(16) float fvc[VNC][32];
    __shared__ unsigned char Mmap[VNC][32];
    __shared__ int ent[VNC];
    __shared__ int lastsh;

    const int tid = threadIdx.x;

    // P0: boundary fvs via sequential matrix application
    if (tid < 32) bfv[0][tid] = (tid == START_TAG) ? 0.f : NEGV;
    __syncthreads();
    for (int c = 0; c < VNC; ++c) {
        MS[tid] = gM[(size_t)c * 1024 + tid];
        __syncthreads();
        if (tid < 32) {
            float m = -3.0e38f;
            #pragma unroll 8
            for (int k = 0; k < 32; ++k)
                m = fmaxf(m, MS[tid * 32 + k] + bfv[c][k]);
            bfv[c + 1][tid] = m;
        }
        __syncthreads();
    }
    if (tid == 0) {
        float bm = -3.0e38f; int bl = 0;
        for (int j = 0; j < 32; ++j) {
            float s2 = bfv[VNC][j] + trans[STOP_TAG * 32 + j];
            if (s2 > bm) { bm = s2; bl = j; }
        }
        out[0] = bm;
        lastsh = bl;
    }
    __syncthreads();

    // P1: per-chunk rescan (exact scan from boundary fv) -> backpointers.
    // 32 threads per chunk (half-wave -> wave-lockstep LDS, no barriers).
    for (int pass = 0; pass < 2; ++pass) {
        const int c = (tid >> 5) + pass * 32;
        const int nt = tid & 31;
        float tr[32];
        #pragma unroll
        for (int k = 0; k < 32; ++k) tr[k] = trans[nt * 32 + k];

        fvc[c][nt] = bfv[c][nt];
        __builtin_amdgcn_wave_barrier();
        asm volatile("" ::: "memory");

        for (int s = 0; s < VCS; ++s) {
            const int t = c * VCS + s;
            float4 v0 = *(const float4*)&fvc[c][0];
            float4 v1 = *(const float4*)&fvc[c][4];
            float4 v2 = *(const float4*)&fvc[c][8];
            float4 v3 = *(const float4*)&fvc[c][12];
            float4 v4 = *(const float4*)&fvc[c][16];
            float4 v5 = *(const float4*)&fvc[c][20];
            float4 v6 = *(const float4*)&fvc[c][24];
            float4 v7 = *(const float4*)&fvc[c][28];
            float fvv[32] = { v0.x, v0.y, v0.z, v0.w, v1.x, v1.y, v1.z, v1.w,
                              v2.x, v2.y, v2.z, v2.w, v3.x, v3.y, v3.z, v3.w,
                              v4.x, v4.y, v4.z, v4.w, v5.x, v5.y, v5.z, v5.w,
                              v6.x, v6.y, v6.z, v6.w, v7.x, v7.y, v7.z, v7.w };
            float m = -3.0e38f; int bi = 0;
            #pragma unroll
            for (int k = 0; k < 32; ++k) {
                float s2 = fvv[k] + tr[k];
                if (s2 > m) { m = s2; bi = k; }     // first-max
            }
            m += feats[(size_t)t * 32 + nt];
            gbp[(size_t)t * 32 + nt] = (unsigned char)bi;
            __builtin_amdgcn_wave_barrier();
            asm volatile("" ::: "memory");
            fvc[c][nt] = m;
            __builtin_amdgcn_wave_barrier();
            asm volatile("" ::: "memory");
        }
        __syncthreads();
    }

    // Phase A: per-chunk entry->exit tag maps
    {
        #pragma unroll
        for (int kk = 0; kk < 2; ++kk) {
            int it = tid + kk * 1024;
            int cc = it >> 5, st = it & 31;
            int cur = st;
            for (int s = VCS - 1; s >= 0; --s)
                cur = gbp[(size_t)(cc * VCS + s) * 32 + cur];
            Mmap[cc][st] = (unsigned char)cur;
        }
    }
    __syncthreads();

    // Phase B: compose chunk maps
    if (tid == 0) {
        int cur = lastsh;
        ent[VNC - 1] = cur;
        for (int cchunk = VNC - 1; cchunk > 0; --cchunk) {
            cur = Mmap[cchunk][cur];
            ent[cchunk - 1] = cur;
        }
    }
    __syncthreads();

    // Phase C: write path
    if (tid < VNC) {
        int cur = ent[tid];
        for (int i = VCS - 1; i >= 0; --i) {
            int t = tid * VCS + i;
            out[1 + t] = (float)cur;
            cur = gbp[(size_t)t * 32 + cur];
        }
    }
}

// ---------------------------------------------------------------------------
extern "C" void kernel_launch(void* const* d_in, const int* in_sizes, int n_in,
                              void* d_out, int out_size, void* d_ws, size_t ws_size,
                              hipStream_t stream)
{
    const int* sent      = (const int*)d_in[0];
    const float* h0      = (const float*)d_in[1];
    const float* c0      = (const float*)d_in[2];
    const float* emb     = (const float*)d_in[3];
    const float* w_ih_f  = (const float*)d_in[4];
    const float* w_hh_f  = (const float*)d_in[5];
    const float* b_f     = (const float*)d_in[6];
    const float* w_ih_b  = (const float*)d_in[7];
    const float* w_hh_b  = (const float*)d_in[8];
    const float* b_b     = (const float*)d_in[9];
    const float* lin_w   = (const float*)d_in[10];
    const float* lin_b   = (const float*)d_in[11];
    const float* trans   = (const float*)d_in[12];
    float* out = (float*)d_out;

    // workspace layout (~25 MB)
    unsigned long long* xgq = (unsigned long long*)d_ws;              // [2][S][256] u64 = 16 MB
    float* hs    = (float*)(xgq + (size_t)2 * S * 256);               // [S][512] f32 = 8 MB
    float* feats = hs + (size_t)S * 512;                              // [S][32] f32 = 0.5 MB
    float* gM    = feats + (size_t)S * T;                             // [64][1024] f32 = 256 KB
    unsigned char* gbp = (unsigned char*)(gM + (size_t)VNC * 1024);   // [S][32] = 128 KB

    xg_kernel<<<dim3(S / SBLK, 2), 256, 0, stream>>>(sent, emb, w_ih_f, b_f, w_ih_b, b_b,
                                                     (unsigned short*)xgq);
    lstm_kernel<<<2, 512, 0, stream>>>(h0, c0, w_hh_f, w_hh_b, xgq, hs);
    feats_kernel<<<S / 8, 256, 0, stream>>>(hs, lin_w, lin_b, feats);
    vit_chunk_kernel<<<VNC, 256, 0, stream>>>(feats, trans, gM);
    vit_combine_kernel<<<1, 1024, 0, stream>>>(feats, trans, gM, gbp, out);
}

// Round 2
// 6311.811 us; speedup vs baseline: 2.2072x; 2.2072x over previous
//
#include <hip/hip_runtime.h>
#include <cstdint>
#include <cstddef>

#define S 4096
#define E 256
#define H 256
#define T 32
#define START_TAG 30
#define STOP_TAG 31
#define NEGV (-10000.0f)

typedef _Float16 half_t;
typedef _Float16 h2 __attribute__((ext_vector_type(2)));
typedef _Float16 f16x8 __attribute__((ext_vector_type(8)));
typedef float f32x4 __attribute__((ext_vector_type(4)));

__device__ __forceinline__ unsigned short f2h16(float f) {
    half_t h = (half_t)f;
    unsigned short u; __builtin_memcpy(&u, &h, 2); return u;
}
__device__ __forceinline__ float h16tof(unsigned short u) {
    half_t h; __builtin_memcpy(&h, &u, 2); return (float)h;
}

__device__ __forceinline__ float sigmoidf_(float x) {
    return 1.0f / (1.0f + __expf(-x));
}
__device__ __forceinline__ float tanhf_(float x) {
    return 1.0f - 2.0f / (__expf(2.0f * x) + 1.0f);
}

__device__ __forceinline__ f16x8 cvt8(float4 a, float4 b) {
    f16x8 v;
    v[0] = (_Float16)a.x; v[1] = (_Float16)a.y; v[2] = (_Float16)a.z; v[3] = (_Float16)a.w;
    v[4] = (_Float16)b.x; v[5] = (_Float16)b.y; v[6] = (_Float16)b.z; v[7] = (_Float16)b.w;
    return v;
}

// ---------------------------------------------------------------------------
// Kernel 1: xg packed f16 per (dir, t, unit): u64 = {i, f, g, o} pre-activations
// ---------------------------------------------------------------------------
#define SBLK 16
__global__ __launch_bounds__(256) void xg_kernel(
    const int* __restrict__ sent, const float* __restrict__ emb,
    const float* __restrict__ w_ih_f, const float* __restrict__ b_f,
    const float* __restrict__ w_ih_b, const float* __restrict__ b_b,
    unsigned short* __restrict__ xg16s)   // [2][S][256][4] ushort
{
    const int dir = blockIdx.y;
    const int t0 = blockIdx.x * SBLK;
    const float* w_ih = dir ? w_ih_b : w_ih_f;
    const float* bias = dir ? b_b : b_f;

    __shared__ float embs[SBLK][E];   // 16 KB
    for (int p = threadIdx.x; p < SBLK * (E / 4); p += 256) {
        int r = p >> 6, kq = p & 63;
        int t = t0 + r;
        int tt = dir ? (S - 1 - t) : t;
        int tok = sent[tt];
        float4 v = *(const float4*)(emb + (size_t)tok * E + 4 * kq);
        *(float4*)&embs[r][4 * kq] = v;
    }
    __syncthreads();

    for (int jj = 0; jj < 4; ++jj) {           // jj = gate index G
        int j = jj * 256 + threadIdx.x;        // gate row
        const float* wrow = w_ih + (size_t)j * E;
        float bv = bias[j];
        float acc[SBLK];
        #pragma unroll
        for (int t = 0; t < SBLK; ++t) acc[t] = bv;

        for (int kc = 0; kc < E / 16; ++kc) {
            float w[16];
            float4 a0 = *(const float4*)(wrow + kc * 16);
            float4 a1 = *(const float4*)(wrow + kc * 16 + 4);
            float4 a2 = *(const float4*)(wrow + kc * 16 + 8);
            float4 a3 = *(const float4*)(wrow + kc * 16 + 12);
            float wv[16] = { a0.x, a0.y, a0.z, a0.w, a1.x, a1.y, a1.z, a1.w,
                             a2.x, a2.y, a2.z, a2.w, a3.x, a3.y, a3.z, a3.w };
            #pragma unroll
            for (int q = 0; q < 16; ++q) w[q] = wv[q];
            #pragma unroll
            for (int t = 0; t < SBLK; ++t) {
                const float* er = &embs[t][kc * 16];
                float s = 0.f;
                #pragma unroll
                for (int q = 0; q < 16; ++q) s += w[q] * er[q];
                acc[t] += s;
            }
        }
        const int u = threadIdx.x;   // unit
        #pragma unroll
        for (int t = 0; t < SBLK; ++t) {
            size_t base = (((size_t)dir * S + (size_t)(t0 + t)) * 256 + u) * 4 + jj;
            xg16s[base] = f2h16(acc[t]);
        }
    }
}

// ---------------------------------------------------------------------------
// Kernel 2: persistent per-direction LSTM via MFMA. 2 blocks x 512 threads.
//
// Per wave w (8 waves): units w*32..w*32+31. 8 MFMA chains; chain c computes
// gate (c&3) of unit w*32 + 2*(lane&15) + (c>>2).
//   A = h broadcast to all 16 rows; B = permuted w_hh rows.
// K = 256 = 8 k-tiles of 32. Register budget (2 waves/SIMD -> 256 regs):
//   kt 0..5 weight fragments in registers  (8 chains x 6 kt x 4 VGPR = 192)
//   kt 6..7 weight fragments in LDS        (128 KB, lane-contiguous uint4)
// acc starts from shared zero; xg added at extraction (no per-chain splats).
// Per-step LDS: 16 distinct b128 (weights) + 8 broadcast b128 (h) per wave.
// ---------------------------------------------------------------------------
#define WLDS_BYTES (8 * 8 * 2 * 64 * 16)          // [w][c][j][lane] uint4 = 131072
#define LSTM_LDS_BYTES (WLDS_BYTES + 2 * 256 * 2) // + double h-buffer (f16) = 132096

__global__ __launch_bounds__(512, 2) void lstm_kernel(
    const float* __restrict__ h0, const float* __restrict__ c0,
    const float* __restrict__ w_hh_f, const float* __restrict__ w_hh_b,
    const unsigned long long* __restrict__ xgq, float* __restrict__ hs)
{
    extern __shared__ char smem[];
    // weight fragment region: [(w*8 + c)*2 + j][lane] uint4
    // h buffers: smem + WLDS_BYTES, 2 x 256 f16

    const int dir  = blockIdx.x;
    const int tid  = threadIdx.x;
    const int lane = tid & 63;
    const int w    = tid >> 6;          // wave 0..7
    const int n    = lane & 15;         // MFMA column
    const int kg   = lane >> 4;         // k-group 0..3
    const float* w_hh = dir ? w_hh_b : w_hh_f;

    // per-lane base of this wave's LDS weight-fragment region
    char* fragp = smem + ((size_t)w * 16 * 1024) + (size_t)lane * 16;

    // ---- one-time weight load: kt 0..5 -> regs, kt 6..7 -> LDS ----
    f16x8 wR[8][6];
    #pragma unroll
    for (int c = 0; c < 8; ++c) {
        const int row = (c & 3) * 256 + w * 32 + 2 * n + (c >> 2);
        const float* pr = w_hh + (size_t)row * H + kg * 8;
        #pragma unroll
        for (int kt = 0; kt < 6; ++kt) {
            float4 a = *(const float4*)(pr + kt * 32);
            float4 b = *(const float4*)(pr + kt * 32 + 4);
            wR[c][kt] = cvt8(a, b);
        }
        #pragma unroll
        for (int j = 0; j < 2; ++j) {
            float4 a = *(const float4*)(pr + (6 + j) * 32);
            float4 b = *(const float4*)(pr + (6 + j) * 32 + 4);
            f16x8 v = cvt8(a, b);
            *(f16x8*)(fragp + (c * 2 + j) * 1024) = v;
        }
    }

    // this lane owns unit u_own (2x redundancy across lanes)
    const int  u_a    = w * 32 + 2 * n;
    const bool hiU    = (kg >= 2);
    const int  u_own  = u_a + (hiU ? 1 : 0);
    const bool writer = (kg == 0) || (kg == 2);
    float cst = c0[dir * H + u_own];

    _Float16* hb0 = (_Float16*)(smem + WLDS_BYTES);
    if (tid < 256) hb0[tid] = (_Float16)h0[dir * H + tid];

    const unsigned long long* xgl = xgq + (size_t)dir * S * 256 + u_own;
    unsigned long long xgw = xgl[0];    // this unit's 4 gates, f16

    __syncthreads();

    for (int t = 0; t < S; ++t) {
        const char* hbp = smem + WLDS_BYTES + ((t & 1) << 9) + kg * 16;

        // prefetch next step's xg during compute
        const int tn = (t + 1 < S) ? (t + 1) : t;
        unsigned long long xgn = xgl[(size_t)tn * 256];

        f32x4 acc[8];
        const f32x4 zc = { 0.f, 0.f, 0.f, 0.f };

        // kt = 6,7 first (weights streamed from LDS; issues reads early)
        {
            f16x8 hA6 = *(const f16x8*)(hbp + 6 * 64);
            f16x8 hA7 = *(const f16x8*)(hbp + 7 * 64);
            #pragma unroll
            for (int c = 0; c < 8; ++c) {
                f16x8 w6 = *(const f16x8*)(fragp + (c * 2 + 0) * 1024);
                f16x8 w7 = *(const f16x8*)(fragp + (c * 2 + 1) * 1024);
                acc[c] = __builtin_amdgcn_mfma_f32_16x16x32_f16(hA6, w6, zc, 0, 0, 0);
                acc[c] = __builtin_amdgcn_mfma_f32_16x16x32_f16(hA7, w7, acc[c], 0, 0, 0);
            }
        }
        // kt = 0..5 from registers
        #pragma unroll
        for (int kt = 0; kt < 6; ++kt) {
            f16x8 hA = *(const f16x8*)(hbp + kt * 64);
            #pragma unroll
            for (int c = 0; c < 8; ++c)
                acc[c] = __builtin_amdgcn_mfma_f32_16x16x32_f16(hA, wR[c][kt], acc[c], 0, 0, 0);
        }

        // unpack this unit's xg pre-activations (4 f16)
        unsigned int lo = (unsigned int)xgw;
        unsigned int hi = (unsigned int)(xgw >> 32);

        // gates for this lane's unit: chains (hiU ? 4..7 : 0..3), element [0]
        float gi = (hiU ? acc[4][0] : acc[0][0]) + h16tof((unsigned short)(lo & 0xffffu));
        float gf = (hiU ? acc[5][0] : acc[1][0]) + h16tof((unsigned short)(lo >> 16));
        float gg = (hiU ? acc[6][0] : acc[2][0]) + h16tof((unsigned short)(hi & 0xffffu));
        float go = (hiU ? acc[7][0] : acc[3][0]) + h16tof((unsigned short)(hi >> 16));

        float iv = sigmoidf_(gi);
        float fv = sigmoidf_(gf);
        float gv = tanhf_(gg);
        float ov = sigmoidf_(go);
        cst = fv * cst + iv * gv;
        float hv = ov * tanhf_(cst);

        if (writer) {
            *(_Float16*)(smem + WLDS_BYTES + (((t + 1) & 1) << 9) + u_own * 2) = (_Float16)hv;
            int row = dir ? (S - 1 - t) : t;
            hs[(size_t)row * 512 + dir * 256 + u_own] = hv;
        }
        xgw = xgn;
        __syncthreads();
    }
}

// ---------------------------------------------------------------------------
// Kernel 3: feats[t][tag] = lin_b[tag] + sum_k hs[t][k] * lin_w[tag][k]
// ---------------------------------------------------------------------------
__global__ __launch_bounds__(256) void feats_kernel(
    const float* __restrict__ hs, const float* __restrict__ lin_w,
    const float* __restrict__ lin_b, float* __restrict__ feats)
{
    const int t0 = blockIdx.x * 8;
    __shared__ float rows[8][512];   // 16 KB
    for (int p = threadIdx.x; p < 8 * 128; p += 256) {
        int r = p >> 7, sg = p & 127;
        float4 v = *(const float4*)(hs + (size_t)(t0 + r) * 512 + sg * 4);
        *(float4*)&rows[r][sg * 4] = v;
    }
    __syncthreads();

    const int tl = threadIdx.x >> 5, tag = threadIdx.x & 31;
    const float* lw = lin_w + (size_t)tag * 512;
    float acc = lin_b[tag];
    for (int kc = 0; kc < 32; ++kc) {
        float4 a0 = *(const float4*)(lw + kc * 16);
        float4 a1 = *(const float4*)(lw + kc * 16 + 4);
        float4 a2 = *(const float4*)(lw + kc * 16 + 8);
        float4 a3 = *(const float4*)(lw + kc * 16 + 12);
        const float* er = &rows[tl][kc * 16];
        acc += a0.x * er[0] + a0.y * er[1] + a0.z * er[2] + a0.w * er[3];
        acc += a1.x * er[4] + a1.y * er[5] + a1.z * er[6] + a1.w * er[7];
        acc += a2.x * er[8] + a2.y * er[9] + a2.z * er[10] + a2.w * er[11];
        acc += a3.x * er[12] + a3.y * er[13] + a3.z * er[14] + a3.w * er[15];
    }
    feats[(size_t)(t0 + tl) * T + tag] = acc;
}

// ---------------------------------------------------------------------------
// Kernel 4a: per-chunk (max,+) transfer matrices. Block c folds steps
// c*64..c*64+63 into M_c[32][32]; A_t[n][p] = trans[n][p] + feats[t][n].
// ---------------------------------------------------------------------------
#define VCS 64
#define VNC (S / VCS)    // 64
__global__ __launch_bounds__(256) void vit_chunk_kernel(
    const float* __restrict__ feats, const float* __restrict__ trans,
    float* __restrict__ gM)
{
    const int c = blockIdx.x;
    const int tid = threadIdx.x;
    const int n = tid >> 3, p0 = (tid & 7) * 4;
    __shared__ float Mb[2][32][36];   // padded rows (144 B, 16-aligned)

    float tr[32];
    #pragma unroll
    for (int k = 0; k < 32; ++k) tr[k] = trans[n * 32 + k];

    float f0 = feats[(size_t)(c * VCS) * 32 + n];
    float4 cur = { tr[p0] + f0, tr[p0 + 1] + f0, tr[p0 + 2] + f0, tr[p0 + 3] + f0 };
    *(float4*)&Mb[0][n][p0] = cur;
    __syncthreads();

    int rb = 0;
    for (int s = 1; s < VCS; ++s) {
        float fn = feats[(size_t)(c * VCS + s) * 32 + n];
        float4 acc = { -3.0e38f, -3.0e38f, -3.0e38f, -3.0e38f };
        #pragma unroll 8
        for (int k = 0; k < 32; ++k) {
            float4 mo = *(const float4*)&Mb[rb][k][p0];
            float tk = tr[k];
            acc.x = fmaxf(acc.x, tk + mo.x);
            acc.y = fmaxf(acc.y, tk + mo.y);
            acc.z = fmaxf(acc.z, tk + mo.z);
            acc.w = fmaxf(acc.w, tk + mo.w);
        }
        acc.x += fn; acc.y += fn; acc.z += fn; acc.w += fn;
        cur = acc;
        *(float4*)&Mb[rb ^ 1][n][p0] = acc;
        rb ^= 1;
        __syncthreads();
    }
    *(float4*)(gM + (size_t)c * 1024 + n * 32 + p0) = cur;
}

// ---------------------------------------------------------------------------
// Kernel 4b: prefix-apply chunk matrices -> boundary fvs; chunk-parallel
// rescan for backpointers; 3-phase backtrack. OUTPUT FLOAT32.
// ---------------------------------------------------------------------------
__global__ __launch_bounds__(1024) void vit_combine_kernel(
    const float* __restrict__ feats, const float* __restrict__ trans,
    const float* __restrict__ gM, unsigned char* __restrict__ gbp,
    float* __restrict__ out)
{
    __shared__ float MS[1024];
    __shared__ __align__(16) float bfv[VNC + 1][32];
    __shared__ __align__(16) float fvc[VNC][32];
    __shared__ unsigned char Mmap[VNC][32];
    __shared__ int ent[VNC];
    __shared__ int lastsh;

    const int tid = threadIdx.x;

    // P0: boundary fvs via sequential matrix application
    if (tid < 32) bfv[0][tid] = (tid == START_TAG) ? 0.f : NEGV;
    __syncthreads();
    for (int c = 0; c < VNC; ++c) {
        MS[tid] = gM[(size_t)c * 1024 + tid];
        __syncthreads();
        if (tid < 32) {
            float m = -3.0e38f;
            #pragma unroll 8
            for (int k = 0; k < 32; ++k)
                m = fmaxf(m, MS[tid * 32 + k] + bfv[c][k]);
            bfv[c + 1][tid] = m;
        }
        __syncthreads();
    }
    if (tid == 0) {
        float bm = -3.0e38f; int bl = 0;
        for (int j = 0; j < 32; ++j) {
            float s2 = bfv[VNC][j] + trans[STOP_TAG * 32 + j];
            if (s2 > bm) { bm = s2; bl = j; }
        }
        out[0] = bm;
        lastsh = bl;
    }
    __syncthreads();

    // P1: per-chunk rescan (exact scan from boundary fv) -> backpointers.
    // 32 threads per chunk (half-wave -> wave-lockstep LDS, no barriers).
    for (int pass = 0; pass < 2; ++pass) {
        const int c = (tid >> 5) + pass * 32;
        const int nt = tid & 31;
        float tr[32];
        #pragma unroll
        for (int k = 0; k < 32; ++k) tr[k] = trans[nt * 32 + k];

        fvc[c][nt] = bfv[c][nt];
        __builtin_amdgcn_wave_barrier();
        asm volatile("" ::: "memory");

        for (int s = 0; s < VCS; ++s) {
            const int t = c * VCS + s;
            float4 v0 = *(const float4*)&fvc[c][0];
            float4 v1 = *(const float4*)&fvc[c][4];
            float4 v2 = *(const float4*)&fvc[c][8];
            float4 v3 = *(const float4*)&fvc[c][12];
            float4 v4 = *(const float4*)&fvc[c][16];
            float4 v5 = *(const float4*)&fvc[c][20];
            float4 v6 = *(const float4*)&fvc[c][24];
            float4 v7 = *(const float4*)&fvc[c][28];
            float fvv[32] = { v0.x, v0.y, v0.z, v0.w, v1.x, v1.y, v1.z, v1.w,
                              v2.x, v2.y, v2.z, v2.w, v3.x, v3.y, v3.z, v3.w,
                              v4.x, v4.y, v4.z, v4.w, v5.x, v5.y, v5.z, v5.w,
                              v6.x, v6.y, v6.z, v6.w, v7.x, v7.y, v7.z, v7.w };
            float m = -3.0e38f; int bi = 0;
            #pragma unroll
            for (int k = 0; k < 32; ++k) {
                float s2 = fvv[k] + tr[k];
                if (s2 > m) { m = s2; bi = k; }     // first-max
            }
            m += feats[(size_t)t * 32 + nt];
            gbp[(size_t)t * 32 + nt] = (unsigned char)bi;
            __builtin_amdgcn_wave_barrier();
            asm volatile("" ::: "memory");
            fvc[c][nt] = m;
            __builtin_amdgcn_wave_barrier();
            asm volatile("" ::: "memory");
        }
        __syncthreads();
    }

    // Phase A: per-chunk entry->exit tag maps
    {
        #pragma unroll
        for (int kk = 0; kk < 2; ++kk) {
            int it = tid + kk * 1024;
            int cc = it >> 5, st = it & 31;
            int cur = st;
            for (int s = VCS - 1; s >= 0; --s)
                cur = gbp[(size_t)(cc * VCS + s) * 32 + cur];
            Mmap[cc][st] = (unsigned char)cur;
        }
    }
    __syncthreads();

    // Phase B: compose chunk maps
    if (tid == 0) {
        int cur = lastsh;
        ent[VNC - 1] = cur;
        for (int cchunk = VNC - 1; cchunk > 0; --cchunk) {
            cur = Mmap[cchunk][cur];
            ent[cchunk - 1] = cur;
        }
    }
    __syncthreads();

    // Phase C: write path
    if (tid < VNC) {
        int cur = ent[tid];
        for (int i = VCS - 1; i >= 0; --i) {
            int t = tid * VCS + i;
            out[1 + t] = (float)cur;
            cur = gbp[(size_t)t * 32 + cur];
        }
    }
}

// ---------------------------------------------------------------------------
extern "C" void kernel_launch(void* const* d_in, const int* in_sizes, int n_in,
                              void* d_out, int out_size, void* d_ws, size_t ws_size,
                              hipStream_t stream)
{
    const int* sent      = (const int*)d_in[0];
    const float* h0      = (const float*)d_in[1];
    const float* c0      = (const float*)d_in[2];
    const float* emb     = (const float*)d_in[3];
    const float* w_ih_f  = (const float*)d_in[4];
    const float* w_hh_f  = (const float*)d_in[5];
    const float* b_f     = (const float*)d_in[6];
    const float* w_ih_b  = (const float*)d_in[7];
    const float* w_hh_b  = (const float*)d_in[8];
    const float* b_b     = (const float*)d_in[9];
    const float* lin_w   = (const float*)d_in[10];
    const float* lin_b   = (const float*)d_in[11];
    const float* trans   = (const float*)d_in[12];
    float* out = (float*)d_out;

    // workspace layout (~25 MB)
    unsigned long long* xgq = (unsigned long long*)d_ws;              // [2][S][256] u64 = 16 MB
    float* hs    = (float*)(xgq + (size_t)2 * S * 256);               // [S][512] f32 = 8 MB
    float* feats = hs + (size_t)S * 512;                              // [S][32] f32 = 0.5 MB
    float* gM    = feats + (size_t)S * T;                             // [64][1024] f32 = 256 KB
    unsigned char* gbp = (unsigned char*)(gM + (size_t)VNC * 1024);   // [S][32] = 128 KB

    hipFuncSetAttribute((const void*)lstm_kernel,
                        hipFuncAttributeMaxDynamicSharedMemorySize, LSTM_LDS_BYTES);

    xg_kernel<<<dim3(S / SBLK, 2), 256, 0, stream>>>(sent, emb, w_ih_f, b_f, w_ih_b, b_b,
                                                     (unsigned short*)xgq);
    lstm_kernel<<<2, 512, LSTM_LDS_BYTES, stream>>>(h0, c0, w_hh_f, w_hh_b, xgq, hs);
    feats_kernel<<<S / 8, 256, 0, stream>>>(hs, lin_w, lin_b, feats);
    vit_chunk_kernel<<<VNC, 256, 0, stream>>>(feats, trans, gM);
    vit_combine_kernel<<<1, 1024, 0, stream>>>(feats, trans, gM, gbp, out);
}